// Round 4
// baseline (212.062 us; speedup 1.0000x reference)
//
#include <hip/hip_runtime.h>

#define BLOCK 256

// clang native vector type — __builtin_nontemporal_load requires this
typedef float f4v __attribute__((ext_vector_type(4)));

// ---------------------------------------------------------------------------
// Block-wide sum reduction: wave64 shuffle reduce, then LDS across waves.
// Returns the full block sum to ALL threads. Re-entrant (entry barrier).
// ---------------------------------------------------------------------------
__device__ __forceinline__ float block_reduce_sum(float v) {
    __shared__ float sm[BLOCK / 64];
    __syncthreads();
#pragma unroll
    for (int off = 32; off > 0; off >>= 1) v += __shfl_down(v, off, 64);
    const int lane = threadIdx.x & 63;
    const int wv = threadIdx.x >> 6;
    if (lane == 0) sm[wv] = v;
    __syncthreads();
    float s = sm[0];
#pragma unroll
    for (int i = 1; i < BLOCK / 64; ++i) s += sm[i];
    return s;
}

__device__ __forceinline__ float sq_sum4(f4v a, f4v b) {
    float dx = a.x - b.x, dy = a.y - b.y, dz = a.z - b.z, dw = a.w - b.w;
    return dx * dx + dy * dy + dz * dz + dw * dw;
}

// ---------------------------------------------------------------------------
// Per-element focal terms around K0:  u = m+K0, inv = rcp(u)
//   S += m ; A += m^3/u^2 ; B += m^3/u^3 ; C += m^3/u^4
// ---------------------------------------------------------------------------
__device__ __forceinline__ void focal_terms(float d, float K0, float& S,
                                            float& A, float& B, float& C) {
    float m = d * d;
    float u = m + K0;
    float inv = __builtin_amdgcn_rcpf(u);
    float m3 = m * m * m;
    float t2 = m3 * inv * inv;
    float t3 = t2 * inv;
    float t4 = t3 * inv;
    S += m; A += t2; B += t3; C += t4;
}

__device__ __forceinline__ void focal4(f4v a, f4v b, float K0, float& S,
                                       float& A, float& B, float& C) {
    focal_terms(a.x - b.x, K0, S, A, B, C);
    focal_terms(a.y - b.y, K0, S, A, B, C);
    focal_terms(a.z - b.z, K0, S, A, B, C);
    focal_terms(a.w - b.w, K0, S, A, B, C);
}

// ---------------------------------------------------------------------------
// Main pass, R10: DUAL-PATH split — alternate grid-stride steps use CACHED
// vs NONTEMPORAL loads (50/50).
// Rationale (R7/R9 post-mortems): pure-NT reads cap at ~3.4 TB/s regardless
// of access shape (contiguous / grid-stride / deep-MLP all neutral). Pure-
// cached reads throttle to 2.6 TB/s DESPITE a measured 50% L3 hit rate
// (FETCH 101.5 of 201.3 MB) — i.e. L3 was serving ~100 MB for free and the
// kernel was still slower. If that throttle is the cached path's own L2
// allocate churn (not a shared inbound-path cap), then dedicating cached
// instructions to half the stream while NT streams the other half engages
// the L3-hit service capacity IN PARALLEL with HBM streaming:
//   cached 100 MB @ >=2.6 (38 us) || NT 100 MB @ 3.4 (29 us) -> main ~44-48.
// If instead the inbound path is the cap, this is neutral -> roofline.
// ---------------------------------------------------------------------------
__global__ void main_pass(const f4v* __restrict__ p,
                          const f4v* __restrict__ t,
                          float* __restrict__ pS, float* __restrict__ pA,
                          float* __restrict__ pB, float* __restrict__ pC,
                          float* __restrict__ pK0,
                          int n4, int gs, int ntail,
                          const float* __restrict__ tp,
                          const float* __restrict__ tt) {
    const int gid = blockIdx.x * BLOCK + threadIdx.x;

    // ---- block-local K0 estimate from iteration 0 (cached loads, kept) ----
    f4v a0{}, b0{};
    float lsum = 0.0f;
    const bool have0 = (gid < n4);
    if (have0) {
        a0 = p[gid];
        b0 = t[gid];
        lsum = sq_sum4(a0, b0);
    }
    float ssum = block_reduce_sum(lsum);
    int nvalid = n4 - blockIdx.x * BLOCK;
    if (nvalid > BLOCK) nvalid = BLOCK;
    if (nvalid < 0) nvalid = 0;
    const float K0 = (nvalid > 0 ? ssum / (4.0f * (float)nvalid) : 0.0f) + 1e-8f;

    // ---- full accumulation around K0: alternating cached / NT steps -------
    float S = 0.0f, A = 0.0f, B = 0.0f, C = 0.0f;
    if (have0) focal4(a0, b0, K0, S, A, B, C);  // iteration-0 contribution

    int i = gid + gs;
    for (; i + gs < n4; i += 2 * gs) {
        // issue all four loads (two paths) before the dependent rcp chains
        f4v xc = p[i];                                   // cached path
        f4v yc = t[i];
        f4v xn = __builtin_nontemporal_load(p + i + gs); // NT path
        f4v yn = __builtin_nontemporal_load(t + i + gs);
        focal4(xc, yc, K0, S, A, B, C);
        focal4(xn, yn, K0, S, A, B, C);
    }
    if (i < n4) {
        f4v x = p[i];
        f4v y = t[i];
        focal4(x, y, K0, S, A, B, C);
    }
    if (blockIdx.x == 0 && threadIdx.x == 0) {
        for (int k = 0; k < ntail; ++k)
            focal_terms(tp[k] - tt[k], K0, S, A, B, C);
    }
    S = block_reduce_sum(S);
    A = block_reduce_sum(A);
    B = block_reduce_sum(B);
    C = block_reduce_sum(C);
    if (threadIdx.x == 0) {
        pS[blockIdx.x] = S;
        pA[blockIdx.x] = A;
        pB[blockIdx.x] = B;
        pC[blockIdx.x] = C;
        pK0[blockIdx.x] = K0;
    }
}

// ---------------------------------------------------------------------------
// Final: global K from exact S, per-block 2nd-order Taylor correction
//   f_b ~= A_b - 2 B_b dK_b + 3 C_b dK_b^2,   dK_b = K - K0_b
// then domain-weight mean (int32/int64 layout sniff: values 0..2 => int64
// high words all zero), scalar output.
// ---------------------------------------------------------------------------
__global__ void final_reduce(const float* __restrict__ pS,
                             const float* __restrict__ pA,
                             const float* __restrict__ pB,
                             const float* __restrict__ pC,
                             const float* __restrict__ pK0, int nb,
                             const int* __restrict__ dom32,
                             const long long* __restrict__ dom64, int Bn,
                             float inv_n, float* __restrict__ out) {
    float s = 0.0f;
    for (int i = threadIdx.x; i < nb; i += blockDim.x) s += pS[i];
    const float K = block_reduce_sum(s) * inv_n + 1e-8f;

    float fsum = 0.0f;
    for (int i = threadIdx.x; i < nb; i += blockDim.x) {
        float dK = K - pK0[i];
        fsum += pA[i] + dK * (-2.0f * pB[i] + 3.0f * pC[i] * dK);
    }
    fsum = block_reduce_sum(fsum);

    __shared__ int is32;
    if (threadIdx.x == 0) is32 = 0;
    __syncthreads();
    if (threadIdx.x < (unsigned)Bn) {
        int v = dom32[threadIdx.x];
        if ((threadIdx.x & 1) && v != 0) atomicOr(&is32, 1);
    }
    __syncthreads();
    float w = 0.0f;
    for (int i = threadIdx.x; i < Bn; i += blockDim.x) {
        int d = is32 ? dom32[i] : (int)dom64[i];
        w += (d == 0) ? 0.6502451783856802f
                      : ((d == 1) ? 1.449137674618944f : 2.509980079602226f);
    }
    float wt = block_reduce_sum(w);

    if (threadIdx.x == 0)
        out[0] = 0.25f * fsum * inv_n * (wt / (float)Bn);
}

extern "C" void kernel_launch(void* const* d_in, const int* in_sizes, int n_in,
                              void* d_out, int out_size, void* d_ws, size_t ws_size,
                              hipStream_t stream) {
    const float* pred = (const float*)d_in[0];
    const float* targ = (const float*)d_in[1];
    const int* dom32 = (const int*)d_in[2];
    const long long* dom64 = (const long long*)d_in[2];

    const int N = in_sizes[0];
    const int n4 = N >> 2;
    const int ntail = N & 3;
    const int Bn = in_sizes[2];
    const float inv_n = 1.0f / (float)N;

    int grid = 2048;  // 8 blocks/CU
    size_t avail = ws_size / sizeof(float);
    while ((size_t)(5 * grid) > avail && grid > 1) grid >>= 1;

    const int gs = grid * BLOCK;  // grid-stride

    float* ws = (float*)d_ws;
    float* pS = ws;
    float* pA = pS + grid;
    float* pB = pA + grid;
    float* pC = pB + grid;
    float* pK0 = pC + grid;

    const float* tail_p = pred + (size_t)n4 * 4;
    const float* tail_t = targ + (size_t)n4 * 4;

    main_pass<<<grid, BLOCK, 0, stream>>>(
        (const f4v*)pred, (const f4v*)targ,
        pS, pA, pB, pC, pK0, n4, gs, ntail, tail_p, tail_t);
    final_reduce<<<1, BLOCK, 0, stream>>>(
        pS, pA, pB, pC, pK0, grid, dom32, dom64, Bn, inv_n, (float*)d_out);
}

// Round 7
// 205.729 us; speedup vs baseline: 1.0308x; 1.0308x over previous
//
#include <hip/hip_runtime.h>

#define BLOCK 256

// clang native vector type — __builtin_nontemporal_load requires this
typedef float f4v __attribute__((ext_vector_type(4)));

// ---------------------------------------------------------------------------
// Block-wide sum reduction: wave64 shuffle reduce, then LDS across waves.
// Returns the full block sum to ALL threads. Re-entrant (entry barrier).
// ---------------------------------------------------------------------------
__device__ __forceinline__ float block_reduce_sum(float v) {
    __shared__ float sm[BLOCK / 64];
    __syncthreads();
#pragma unroll
    for (int off = 32; off > 0; off >>= 1) v += __shfl_down(v, off, 64);
    const int lane = threadIdx.x & 63;
    const int wv = threadIdx.x >> 6;
    if (lane == 0) sm[wv] = v;
    __syncthreads();
    float s = sm[0];
#pragma unroll
    for (int i = 1; i < BLOCK / 64; ++i) s += sm[i];
    return s;
}

__device__ __forceinline__ float sq_sum4(f4v a, f4v b) {
    float dx = a.x - b.x, dy = a.y - b.y, dz = a.z - b.z, dw = a.w - b.w;
    return dx * dx + dy * dy + dz * dz + dw * dw;
}

// ---------------------------------------------------------------------------
// Per-element focal terms around K0:  u = m+K0, inv = rcp(u)
//   S += m ; A += m^3/u^2 ; B += m^3/u^3 ; C += m^3/u^4
// ---------------------------------------------------------------------------
__device__ __forceinline__ void focal_terms(float d, float K0, float& S,
                                            float& A, float& B, float& C) {
    float m = d * d;
    float u = m + K0;
    float inv = __builtin_amdgcn_rcpf(u);
    float m3 = m * m * m;
    float t2 = m3 * inv * inv;
    float t3 = t2 * inv;
    float t4 = t3 * inv;
    S += m; A += t2; B += t3; C += t4;
}

__device__ __forceinline__ void focal4(f4v a, f4v b, float K0, float& S,
                                       float& A, float& B, float& C) {
    focal_terms(a.x - b.x, K0, S, A, B, C);
    focal_terms(a.y - b.y, K0, S, A, B, C);
    focal_terms(a.z - b.z, K0, S, A, B, C);
    focal_terms(a.w - b.w, K0, S, A, B, C);
}

// ---------------------------------------------------------------------------
// Main pass, R12 = R9 restored (grid-stride NT; verified 205.7 us, passed).
// Session ledger of read-path probes (all full occupancy, 32 waves/CU):
//   cached (50% L3 hit)            2.6 TB/s   (R1)
//   NT contiguous                  ~3.4       (R0/R6-form)
//   NT contiguous + 8-deep MLP     ~3.4       (R2)
//   NT grid-stride                 ~3.4       (R3)
//   dual-path cached-L3 || NT-HBM  ~3.3       (R4; FETCH 98 MB, time flat)
// => vector-read return ceiling ~3.4 TB/s: pattern-, MLP-, and source-
//    insensitive. main_pass = 201.3 MB / 3.4 TB/s ~= 59-60 us = observed.
// R11's global_load_lds probe killed its container twice (DMA-path fault
// suspected) and its mechanism shares the same vmcnt/TA/L2 request path —
// abandoned. This kernel is the measured roofline configuration.
// ---------------------------------------------------------------------------
__global__ void main_pass(const f4v* __restrict__ p,
                          const f4v* __restrict__ t,
                          float* __restrict__ pS, float* __restrict__ pA,
                          float* __restrict__ pB, float* __restrict__ pC,
                          float* __restrict__ pK0,
                          int n4, int gs, int ntail,
                          const float* __restrict__ tp,
                          const float* __restrict__ tt) {
    const int gid = blockIdx.x * BLOCK + threadIdx.x;

    // ---- block-local K0 estimate from iteration 0 (cached loads, kept) ----
    f4v a0{}, b0{};
    float lsum = 0.0f;
    const bool have0 = (gid < n4);
    if (have0) {
        a0 = p[gid];
        b0 = t[gid];
        lsum = sq_sum4(a0, b0);
    }
    float ssum = block_reduce_sum(lsum);
    int nvalid = n4 - blockIdx.x * BLOCK;
    if (nvalid > BLOCK) nvalid = BLOCK;
    if (nvalid < 0) nvalid = 0;
    const float K0 = (nvalid > 0 ? ssum / (4.0f * (float)nvalid) : 0.0f) + 1e-8f;

    // ---- full accumulation around K0, NT grid-stride streaming ------------
    float S = 0.0f, A = 0.0f, B = 0.0f, C = 0.0f;
    if (have0) focal4(a0, b0, K0, S, A, B, C);  // iteration-0 contribution

    for (int i = gid + gs; i < n4; i += gs) {
        f4v x = __builtin_nontemporal_load(p + i);
        f4v y = __builtin_nontemporal_load(t + i);
        focal4(x, y, K0, S, A, B, C);
    }
    if (blockIdx.x == 0 && threadIdx.x == 0) {
        for (int k = 0; k < ntail; ++k)
            focal_terms(tp[k] - tt[k], K0, S, A, B, C);
    }
    S = block_reduce_sum(S);
    A = block_reduce_sum(A);
    B = block_reduce_sum(B);
    C = block_reduce_sum(C);
    if (threadIdx.x == 0) {
        pS[blockIdx.x] = S;
        pA[blockIdx.x] = A;
        pB[blockIdx.x] = B;
        pC[blockIdx.x] = C;
        pK0[blockIdx.x] = K0;
    }
}

// ---------------------------------------------------------------------------
// Final: global K from exact S, per-block 2nd-order Taylor correction
//   f_b ~= A_b - 2 B_b dK_b + 3 C_b dK_b^2,   dK_b = K - K0_b
// then domain-weight mean (int32/int64 layout sniff: values 0..2 => int64
// high words all zero), scalar output.
// ---------------------------------------------------------------------------
__global__ void final_reduce(const float* __restrict__ pS,
                             const float* __restrict__ pA,
                             const float* __restrict__ pB,
                             const float* __restrict__ pC,
                             const float* __restrict__ pK0, int nb,
                             const int* __restrict__ dom32,
                             const long long* __restrict__ dom64, int Bn,
                             float inv_n, float* __restrict__ out) {
    float s = 0.0f;
    for (int i = threadIdx.x; i < nb; i += blockDim.x) s += pS[i];
    const float K = block_reduce_sum(s) * inv_n + 1e-8f;

    float fsum = 0.0f;
    for (int i = threadIdx.x; i < nb; i += blockDim.x) {
        float dK = K - pK0[i];
        fsum += pA[i] + dK * (-2.0f * pB[i] + 3.0f * pC[i] * dK);
    }
    fsum = block_reduce_sum(fsum);

    __shared__ int is32;
    if (threadIdx.x == 0) is32 = 0;
    __syncthreads();
    if (threadIdx.x < (unsigned)Bn) {
        int v = dom32[threadIdx.x];
        if ((threadIdx.x & 1) && v != 0) atomicOr(&is32, 1);
    }
    __syncthreads();
    float w = 0.0f;
    for (int i = threadIdx.x; i < Bn; i += blockDim.x) {
        int d = is32 ? dom32[i] : (int)dom64[i];
        w += (d == 0) ? 0.6502451783856802f
                      : ((d == 1) ? 1.449137674618944f : 2.509980079602226f);
    }
    float wt = block_reduce_sum(w);

    if (threadIdx.x == 0)
        out[0] = 0.25f * fsum * inv_n * (wt / (float)Bn);
}

extern "C" void kernel_launch(void* const* d_in, const int* in_sizes, int n_in,
                              void* d_out, int out_size, void* d_ws, size_t ws_size,
                              hipStream_t stream) {
    const float* pred = (const float*)d_in[0];
    const float* targ = (const float*)d_in[1];
    const int* dom32 = (const int*)d_in[2];
    const long long* dom64 = (const long long*)d_in[2];

    const int N = in_sizes[0];
    const int n4 = N >> 2;
    const int ntail = N & 3;
    const int Bn = in_sizes[2];
    const float inv_n = 1.0f / (float)N;

    int grid = 2048;  // 8 blocks/CU
    size_t avail = ws_size / sizeof(float);
    while ((size_t)(5 * grid) > avail && grid > 1) grid >>= 1;

    const int gs = grid * BLOCK;  // grid-stride

    float* ws = (float*)d_ws;
    float* pS = ws;
    float* pA = pS + grid;
    float* pB = pA + grid;
    float* pC = pB + grid;
    float* pK0 = pC + grid;

    const float* tail_p = pred + (size_t)n4 * 4;
    const float* tail_t = targ + (size_t)n4 * 4;

    main_pass<<<grid, BLOCK, 0, stream>>>(
        (const f4v*)pred, (const f4v*)targ,
        pS, pA, pB, pC, pK0, n4, gs, ntail, tail_p, tail_t);
    final_reduce<<<1, BLOCK, 0, stream>>>(
        pS, pA, pB, pC, pK0, grid, dom32, dom64, Bn, inv_n, (float*)d_out);
}